// Round 3
// baseline (94.592 us; speedup 1.0000x reference)
//
#include <hip/hip_runtime.h>

#define B_TOT   4096
#define NSTEPS  4
#define E       128
#define OUT_DIM 16
#define NMOD    64
#define KSPLIT  8
#define TILE    16

// ws layout:
//   int  cnt [4][64]      at int-offset 0
//   int  off [4][64]      at int-offset 256
//   int  perm[4][4096]    at int-offset 512
//   float xbuf[4096][128] at byte-offset (512+16384)*4 = 67584 (16B aligned)

__global__ __launch_bounds__(1024) void sort_kernel(const int* __restrict__ mids,
                                                    int* __restrict__ ws)
{
    const int s = blockIdx.x;       // step
    const int t = threadIdx.x;
    __shared__ int h[NMOD];
    __shared__ int o[NMOD];
    if (t < NMOD) h[t] = 0;
    __syncthreads();
    for (int b = t; b < B_TOT; b += 1024)
        atomicAdd(&h[mids[b * NSTEPS + s]], 1);
    __syncthreads();
    if (t == 0) {
        int run = 0;
        for (int m = 0; m < NMOD; ++m) { o[m] = run; run += h[m]; }
    }
    __syncthreads();
    if (t < NMOD) {
        ws[s * NMOD + t]       = h[t];   // cnt
        ws[256 + s * NMOD + t] = o[t];   // off
        h[t] = o[t];                     // reuse as cursor
    }
    __syncthreads();
    int* perm = ws + 512 + s * B_TOT;
    for (int b = t; b < B_TOT; b += 1024) {
        const int m = mids[b * NSTEPS + s];
        const int p = atomicAdd(&h[m], 1);
        perm[p] = b;
    }
}

template <bool FIRST, bool LAST>
__global__ __launch_bounds__(256) void step_kernel(
    const int s,
    const int* __restrict__ ws,
    const int* __restrict__ author_ids,
    const float* __restrict__ embed,
    const float* __restrict__ W,
    const float* __restrict__ bias,
    const float* __restrict__ cls_W,
    const float* __restrict__ cls_b,
    float* __restrict__ xbuf,
    float* __restrict__ out)
{
    const int m = blockIdx.x / KSPLIT;
    const int k = blockIdx.x % KSPLIT;
    const int cnt = ws[s * NMOD + m];
    const int off = ws[256 + s * NMOD + m];
    const int start = off + k * TILE;
    const int end   = off + cnt;
    if (start >= end) return;        // uniform across block (no barriers yet)

    const int t = threadIdx.x;

    // W tile XOR-swizzled: logical (row, j4) stored at float4 slot (row<<5)|(j4^(row&7)).
    // Column-indexed b128 reads then spread 8 consecutive rows over all 32 banks.
    __shared__ __align__(16) float Wl[E][E];      // 64 KB
    __shared__ __align__(16) float Xl[TILE][E];   // 8 KB
    __shared__ __align__(16) float bl[E];
    __shared__ int rowb[TILE];

    // ---- stage W[m] (swizzled) and bias into LDS ----
    {
        const float4* __restrict__ wg = (const float4*)(W + (size_t)m * E * E);
        float4* __restrict__ wl4 = (float4*)Wl;
        #pragma unroll
        for (int i = 0; i < 16; ++i) {
            const int c4  = i * 256 + t;          // float4 index 0..4095
            const int row = c4 >> 5;
            const int j4  = c4 & 31;
            wl4[(row << 5) | (j4 ^ (row & 7))] = wg[c4];
        }
        if (t < 32)
            ((float4*)bl)[t] = ((const float4*)(bias + m * E))[t];
    }

    const int* __restrict__ perm = ws + 512 + s * B_TOT;

    const int cc = t & 63;          // col pair: cc and cc+64 (lanes span wave)
    const int rq = t >> 6;          // row quad: rows rq*4 .. rq*4+3 (uniform/wave)
    const int sw = cc & 7;          // swizzle key (same for cc and cc+64)
    const int xi = t >> 4;          // staging: row
    const int xj = t & 15;          // staging: 32B chunk

    for (int base = start; base < end; base += KSPLIT * TILE) {
        const int nb = min(TILE, end - base);

        // ---- stage up to 16 x-rows (16 threads per row, 32B each) ----
        if (xi < nb) {
            const int b = perm[base + xi];
            if (xj == 0) rowb[xi] = b;
            const float* __restrict__ src =
                FIRST ? (embed + (size_t)author_ids[b] * E)
                      : (xbuf + (size_t)b * E);
            const float4 v0 = ((const float4*)src)[2 * xj];
            const float4 v1 = ((const float4*)src)[2 * xj + 1];
            *(float4*)&Xl[xi][xj * 8]     = v0;
            *(float4*)&Xl[xi][xj * 8 + 4] = v1;
        } else {
            const float4 z = {0.f, 0.f, 0.f, 0.f};
            *(float4*)&Xl[xi][xj * 8]     = z;
            *(float4*)&Xl[xi][xj * 8 + 4] = z;
        }
        __syncthreads();   // first iteration also covers W/bias staging

        // ---- 16x128 tile: thread = (2 cols) x (4 rows) ----
        float a0[4] = {0, 0, 0, 0};
        float a1[4] = {0, 0, 0, 0};
        #pragma unroll 8
        for (int j4 = 0; j4 < 32; ++j4) {
            const int pj = (j4 ^ sw) * 4;
            const float4 w0 = *(const float4*)&Wl[cc][pj];
            const float4 w1 = *(const float4*)&Wl[cc + 64][pj];
            #pragma unroll
            for (int r = 0; r < 4; ++r) {
                const float4 x4 = *(const float4*)&Xl[rq * 4 + r][j4 * 4]; // wave-uniform broadcast
                a0[r] += w0.x * x4.x + w0.y * x4.y + w0.z * x4.z + w0.w * x4.w;
                a1[r] += w1.x * x4.x + w1.y * x4.y + w1.z * x4.z + w1.w * x4.w;
            }
        }
        const float b0 = bl[cc];
        const float b1 = bl[cc + 64];

        if (!LAST) {
            #pragma unroll
            for (int r = 0; r < 4; ++r) {
                const int row = rq * 4 + r;
                if (row < nb) {
                    float* __restrict__ dst = xbuf + (size_t)rowb[row] * E;
                    dst[cc]      = tanhf(a0[r] + b0);
                    dst[cc + 64] = tanhf(a1[r] + b1);
                }
            }
            __syncthreads();   // X readers done before next subtile overwrites
        } else {
            __syncthreads();   // all X reads done
            #pragma unroll
            for (int r = 0; r < 4; ++r) {
                const int row = rq * 4 + r;
                Xl[row][cc]      = a0[r] + b0;   // y into Xl
                Xl[row][cc + 64] = a1[r] + b1;
            }
            __syncthreads();
            // ---- fused classifier: thread (row, j) ----
            const int row = t >> 4;
            const int j = t & 15;
            if (row < nb) {
                const float4* __restrict__ cw = (const float4*)(cls_W + j * E);
                float a2 = 0.f;
                #pragma unroll 8
                for (int jj = 0; jj < 32; ++jj) {
                    const float4 y4 = *(const float4*)&Xl[row][jj * 4];  // 16-lane broadcast
                    const float4 w4 = cw[jj];                            // L1-resident, 8 KB
                    a2 += y4.x * w4.x + y4.y * w4.y + y4.z * w4.z + y4.w * w4.w;
                }
                out[(size_t)rowb[row] * OUT_DIM + j] = a2 + cls_b[j];
            }
            __syncthreads();
        }
    }
}

extern "C" void kernel_launch(void* const* d_in, const int* in_sizes, int n_in,
                              void* d_out, int out_size, void* d_ws, size_t ws_size,
                              hipStream_t stream) {
    const int*   author_ids = (const int*)d_in[0];
    const int*   module_ids = (const int*)d_in[1];
    const float* embed      = (const float*)d_in[2];
    const float* W          = (const float*)d_in[3];
    const float* bias       = (const float*)d_in[4];
    const float* cls_W      = (const float*)d_in[5];
    const float* cls_b      = (const float*)d_in[6];
    float* out = (float*)d_out;

    int*   wsI  = (int*)d_ws;
    float* xbuf = (float*)((char*)d_ws + (512 + NSTEPS * B_TOT) * sizeof(int));

    sort_kernel<<<NSTEPS, 1024, 0, stream>>>(module_ids, wsI);

    const dim3 g(NMOD * KSPLIT), blk(256);
    step_kernel<true,  false><<<g, blk, 0, stream>>>(0, wsI, author_ids, embed, W, bias, cls_W, cls_b, xbuf, out);
    step_kernel<false, false><<<g, blk, 0, stream>>>(1, wsI, author_ids, embed, W, bias, cls_W, cls_b, xbuf, out);
    step_kernel<false, false><<<g, blk, 0, stream>>>(2, wsI, author_ids, embed, W, bias, cls_W, cls_b, xbuf, out);
    step_kernel<false, true ><<<g, blk, 0, stream>>>(3, wsI, author_ids, embed, W, bias, cls_W, cls_b, xbuf, out);
}

// Round 4
// 48.141 us; speedup vs baseline: 1.9649x; 1.9649x over previous
//
#include <hip/hip_runtime.h>

#define B_TOT   4096
#define NSTEPS  4
#define E       128
#define OUT_DIM 16
#define NMOD    64
#define KSPLIT  8
#define TILE    16

using frag8 = __attribute__((ext_vector_type(8))) short;   // 8 bf16 (4 VGPRs)
using f32x4 = __attribute__((ext_vector_type(4))) float;

__device__ __forceinline__ unsigned short f2bf(float x) {
    union { float f; unsigned u; } v; v.f = x;
    unsigned r = v.u + 0x7FFFu + ((v.u >> 16) & 1u);   // round-to-nearest-even
    return (unsigned short)(r >> 16);
}
__device__ __forceinline__ float bf2f(unsigned short h) {
    union { unsigned u; float f; } v; v.u = ((unsigned)h) << 16;
    return v.f;
}
__device__ __forceinline__ unsigned pack2(unsigned short a, unsigned short b) {
    return (unsigned)a | ((unsigned)b << 16);
}
__device__ __forceinline__ float tanh_fast(float x) {
    return 1.0f - 2.0f / (__expf(2.0f * x) + 1.0f);
}

// ws layout:
//   int  cnt [4][64]      at int-offset 0
//   int  off [4][64]      at int-offset 256
//   int  perm[4][4096]    at int-offset 512
//   float xbuf[4096][128] at byte-offset (512+16384)*4 = 67584

__global__ __launch_bounds__(1024) void sort_kernel(const int* __restrict__ mids,
                                                    int* __restrict__ ws)
{
    const int s = blockIdx.x;
    const int t = threadIdx.x;
    __shared__ int h[NMOD];
    __shared__ int o[NMOD];
    if (t < NMOD) h[t] = 0;
    __syncthreads();
    for (int b = t; b < B_TOT; b += 1024)
        atomicAdd(&h[mids[b * NSTEPS + s]], 1);
    __syncthreads();
    if (t == 0) {
        int run = 0;
        for (int m = 0; m < NMOD; ++m) { o[m] = run; run += h[m]; }
    }
    __syncthreads();
    if (t < NMOD) {
        ws[s * NMOD + t]       = h[t];
        ws[256 + s * NMOD + t] = o[t];
        h[t] = o[t];
    }
    __syncthreads();
    int* perm = ws + 512 + s * B_TOT;
    for (int b = t; b < B_TOT; b += 1024) {
        const int m = mids[b * NSTEPS + s];
        const int p = atomicAdd(&h[m], 1);
        perm[p] = b;
    }
}

template <bool FIRST, bool LAST>
__global__ __launch_bounds__(256) void step_kernel(
    const int s,
    const int* __restrict__ ws,
    const int* __restrict__ author_ids,
    const float* __restrict__ embed,
    const float* __restrict__ W,
    const float* __restrict__ bias,
    const float* __restrict__ cls_W,
    const float* __restrict__ cls_b,
    float* __restrict__ xbuf,
    float* __restrict__ out)
{
    const int m = blockIdx.x >> 3;       // / KSPLIT
    const int k = blockIdx.x & (KSPLIT - 1);
    const int cnt = ws[s * NMOD + m];
    const int off = ws[256 + s * NMOD + m];
    const int start = off + k * TILE;
    const int end   = off + cnt;
    if (start >= end) return;            // uniform across block

    const int t  = threadIdx.x;
    const int w  = t >> 6;               // wave 0..3
    const int l  = t & 63;
    const int g  = l >> 4;               // k-group 0..3
    const int r0 = l & 15;               // fragment row/col index

    // bf16 tiles, 16B-unit XOR swizzle: unit u of row c stored at u ^ (c&15)
    __shared__ __align__(16) unsigned short Whi[E * E];   // 32 KB
    __shared__ __align__(16) unsigned short Wlo[E * E];   // 32 KB
    __shared__ __align__(16) unsigned short Xhi[TILE * E];
    __shared__ __align__(16) unsigned short Xlo[TILE * E];
    __shared__ __align__(16) float bl[E];
    __shared__ int rowb[TILE];
    __shared__ __align__(16) float YlS[LAST ? TILE * (E + 4) : 1];
    __shared__ __align__(16) float cwlS[LAST ? OUT_DIM * (E + 4) : 1];

    // ---- stage W[m] as bf16 hi/lo (swizzled) + bias ----
    {
        const f32x4* __restrict__ wg = (const f32x4*)(W + (size_t)m * E * E);
        #pragma unroll
        for (int i = 0; i < 16; ++i) {
            const f32x4 v = wg[i * 256 + t];
            const int f  = (i * 256 + t) * 4;     // flat f32 index
            const int c  = f >> 7;                // W row (output col)
            const int kk = f & 127;               // W col (k)
            const int idx = c * E + (((kk >> 3) ^ (c & 15)) << 3) + (kk & 7);
            const unsigned short h0 = f2bf(v.x), h1 = f2bf(v.y),
                                 h2 = f2bf(v.z), h3 = f2bf(v.w);
            const unsigned short q0 = f2bf(v.x - bf2f(h0)), q1 = f2bf(v.y - bf2f(h1)),
                                 q2 = f2bf(v.z - bf2f(h2)), q3 = f2bf(v.w - bf2f(h3));
            uint2 hp = { pack2(h0, h1), pack2(h2, h3) };
            uint2 lp = { pack2(q0, q1), pack2(q2, q3) };
            *(uint2*)&Whi[idx] = hp;
            *(uint2*)&Wlo[idx] = lp;
        }
        if (t < 32)
            ((f32x4*)bl)[t] = ((const f32x4*)(bias + m * E))[t];
        if (LAST) {   // stage cls_W 16x128 -> [16][132]
            #pragma unroll
            for (int i = 0; i < 2; ++i) {
                const int fi = i * 256 + t;       // float4 index
                const f32x4 v = ((const f32x4*)cls_W)[fi];
                const int j  = (fi * 4) >> 7;
                const int kk = (fi * 4) & 127;
                *(f32x4*)&cwlS[j * (E + 4) + kk] = v;
            }
        }
    }

    const int* __restrict__ perm = ws + 512 + s * B_TOT;
    const int c0 = 32 * w + r0;          // this lane's first output col
    const int c1 = c0 + 16;

    for (int base = start; base < end; base += KSPLIT * TILE) {
        const int nb = min(TILE, end - base);

        // ---- stage X tile -> bf16 hi/lo (swizzled); zero pad rows ----
        {
            const int row = t >> 4, u0 = t & 15;
            f32x4 v0 = {0.f, 0.f, 0.f, 0.f}, v1 = {0.f, 0.f, 0.f, 0.f};
            if (row < nb) {
                const int b = perm[base + row];
                if (u0 == 0) rowb[row] = b;
                const float* __restrict__ src =
                    FIRST ? (embed + (size_t)author_ids[b] * E)
                          : (xbuf + (size_t)b * E);
                v0 = ((const f32x4*)src)[u0 * 2];
                v1 = ((const f32x4*)src)[u0 * 2 + 1];
            }
            const float xf[8] = {v0.x, v0.y, v0.z, v0.w, v1.x, v1.y, v1.z, v1.w};
            unsigned short hh[8], qq[8];
            #pragma unroll
            for (int j = 0; j < 8; ++j) {
                hh[j] = f2bf(xf[j]);
                qq[j] = f2bf(xf[j] - bf2f(hh[j]));
            }
            const int idx = row * E + ((u0 ^ row) << 3);
            uint4 hp = { pack2(hh[0], hh[1]), pack2(hh[2], hh[3]),
                         pack2(hh[4], hh[5]), pack2(hh[6], hh[7]) };
            uint4 lp = { pack2(qq[0], qq[1]), pack2(qq[2], qq[3]),
                         pack2(qq[4], qq[5]), pack2(qq[6], qq[7]) };
            *(uint4*)&Xhi[idx] = hp;
            *(uint4*)&Xlo[idx] = lp;
        }
        __syncthreads();                 // X (and first-iter W) visible

        // ---- A fragments: X[row=r0][k = 32*ss + 8*g + b] ----
        frag8 ahi[4], alo[4];
        #pragma unroll
        for (int ss = 0; ss < 4; ++ss) {
            const int idx = r0 * E + (((4 * ss + g) ^ r0) << 3);
            ahi[ss] = *(const frag8*)&Xhi[idx];
            alo[ss] = *(const frag8*)&Xlo[idx];
        }

        // ---- MFMA: acc = Xhi*Whi + Xlo*Whi + Xhi*Wlo ----
        f32x4 acc0 = {0.f, 0.f, 0.f, 0.f};
        f32x4 acc1 = {0.f, 0.f, 0.f, 0.f};
        #pragma unroll
        for (int ss = 0; ss < 4; ++ss) {
            const int u = ((4 * ss + g) ^ r0) << 3;
            {
                const int idx = c0 * E + u;
                const frag8 bh = *(const frag8*)&Whi[idx];
                const frag8 bq = *(const frag8*)&Wlo[idx];
                acc0 = __builtin_amdgcn_mfma_f32_16x16x32_bf16(ahi[ss], bh, acc0, 0, 0, 0);
                acc0 = __builtin_amdgcn_mfma_f32_16x16x32_bf16(alo[ss], bh, acc0, 0, 0, 0);
                acc0 = __builtin_amdgcn_mfma_f32_16x16x32_bf16(ahi[ss], bq, acc0, 0, 0, 0);
            }
            {
                const int idx = c1 * E + u;
                const frag8 bh = *(const frag8*)&Whi[idx];
                const frag8 bq = *(const frag8*)&Wlo[idx];
                acc1 = __builtin_amdgcn_mfma_f32_16x16x32_bf16(ahi[ss], bh, acc1, 0, 0, 0);
                acc1 = __builtin_amdgcn_mfma_f32_16x16x32_bf16(alo[ss], bh, acc1, 0, 0, 0);
                acc1 = __builtin_amdgcn_mfma_f32_16x16x32_bf16(ahi[ss], bq, acc1, 0, 0, 0);
            }
        }

        // ---- epilogue: D row = 4*g + r, col = c0/c1 ----
        if (!LAST) {
            const float b0 = bl[c0], b1 = bl[c1];
            #pragma unroll
            for (int r = 0; r < 4; ++r) {
                const int row = 4 * g + r;
                if (row < nb) {
                    float* __restrict__ dst = xbuf + (size_t)rowb[row] * E;
                    dst[c0] = tanh_fast(acc0[r] + b0);
                    dst[c1] = tanh_fast(acc1[r] + b1);
                }
            }
            __syncthreads();             // rowb/X LDS free for next iter
        } else {
            const float b0 = bl[c0], b1 = bl[c1];
            #pragma unroll
            for (int r = 0; r < 4; ++r) {
                const int row = 4 * g + r;
                YlS[row * (E + 4) + c0] = acc0[r] + b0;
                YlS[row * (E + 4) + c1] = acc1[r] + b1;
            }
            __syncthreads();
            // fused classifier: thread (row, j)
            const int row = t >> 4, j = t & 15;
            if (row < nb) {
                float a2 = cls_b[j];
                #pragma unroll 8
                for (int jj = 0; jj < 32; ++jj) {
                    const f32x4 y4 = *(const f32x4*)&YlS[row * (E + 4) + jj * 4];
                    const f32x4 w4 = *(const f32x4*)&cwlS[j * (E + 4) + jj * 4];
                    a2 += y4.x * w4.x + y4.y * w4.y + y4.z * w4.z + y4.w * w4.w;
                }
                out[(size_t)rowb[row] * OUT_DIM + j] = a2;
            }
            __syncthreads();
        }
    }
}

extern "C" void kernel_launch(void* const* d_in, const int* in_sizes, int n_in,
                              void* d_out, int out_size, void* d_ws, size_t ws_size,
                              hipStream_t stream) {
    const int*   author_ids = (const int*)d_in[0];
    const int*   module_ids = (const int*)d_in[1];
    const float* embed      = (const float*)d_in[2];
    const float* W          = (const float*)d_in[3];
    const float* bias       = (const float*)d_in[4];
    const float* cls_W      = (const float*)d_in[5];
    const float* cls_b      = (const float*)d_in[6];
    float* out = (float*)d_out;

    int*   wsI  = (int*)d_ws;
    float* xbuf = (float*)((char*)d_ws + (512 + NSTEPS * B_TOT) * sizeof(int));

    sort_kernel<<<NSTEPS, 1024, 0, stream>>>(module_ids, wsI);

    const dim3 g(NMOD * KSPLIT), blk(256);
    step_kernel<true,  false><<<g, blk, 0, stream>>>(0, wsI, author_ids, embed, W, bias, cls_W, cls_b, xbuf, out);
    step_kernel<false, false><<<g, blk, 0, stream>>>(1, wsI, author_ids, embed, W, bias, cls_W, cls_b, xbuf, out);
    step_kernel<false, false><<<g, blk, 0, stream>>>(2, wsI, author_ids, embed, W, bias, cls_W, cls_b, xbuf, out);
    step_kernel<false, true ><<<g, blk, 0, stream>>>(3, wsI, author_ids, embed, W, bias, cls_W, cls_b, xbuf, out);
}